// Round 7
// baseline (70.258 us; speedup 1.0000x reference)
//
#include <hip/hip_runtime.h>
#include <hip/hip_bf16.h>

#define T_IN   16
#define T_OUT  25
#define BHERO  4096
#define K_NBR  32
#define N_NBR  (BHERO * K_NBR)
#define ENC    64
#define DEC    128
#define DYN    32
#define EMB    32
#define HEROES 8          // heroes per WG (M=8 of 16 MFMA rows used; trans redistributed)

#define EROW   104        // encoder slab row: [emb 32 | h 64] + pad (208 B)
#define DROW   136        // decoder slab row: 128 bf16 + pad (272 B)
#define RROW   40         // rela row: 32 feat + 8 pad (80 B)
#define SLABE  (HEROES * EROW)   // shorts per encoder slab (1664 B)
#define SLABD  (HEROES * DROW)   // shorts per decoder slab (2176 B)

// ---- LDS layout (byte offsets; phases overlay) ----
// Encoder phase: slab[17][8][EROW] @0 (28288) | rela[256][RROW] @28288 (20480) | pmax[16][64] @48768 (4096)
// Decoder phase: hist_s[26][8][DROW] @0 (56576)  (overlays all of the above once dead)
// Persistent:    enc_s[8][68] @56576 | wop[2][128] @58752 | wip[32][2] @59776 | bip @60032 | bop @60160
#define OFF_RELA   28288
#define OFF_PMAX   48768
#define OFF_ENC    56576
#define OFF_WOP    58752
#define OFF_WIP    59776
#define OFF_BIP    60032
#define OFF_BOP    60160
#define LDS_TOTAL  60176

typedef __attribute__((ext_vector_type(8))) short bf16x8;   // 8 bf16 in 4 VGPRs
typedef __attribute__((ext_vector_type(4))) float f32x4;    // MFMA 16x16 C/D frag

__device__ __forceinline__ float lrelu(float x) { return x >= 0.f ? x : 0.1f * x; }
__device__ __forceinline__ float rcpf(float x)  { return __builtin_amdgcn_rcpf(x); }
__device__ __forceinline__ float sigm(float x)  { return rcpf(1.f + __expf(-x)); }
__device__ __forceinline__ float tanhv(float x) {
    return fmaf(2.f, rcpf(1.f + __expf(-2.f * x)), -1.f);
}
__device__ __forceinline__ short f2bf(float x) {
    __hip_bfloat16 b = __float2bfloat16(x);
    short s; __builtin_memcpy(&s, &b, 2); return s;
}
__device__ __forceinline__ unsigned pk2(float lo, float hi) {
    __hip_bfloat162 p = __float22bfloat162_rn(make_float2(lo, hi));
    unsigned u; __builtin_memcpy(&u, &p, 4); return u;
}
__device__ __forceinline__ bf16x8 mk_frag(float4 f0, float4 f1) {
    uint4 v = { pk2(f0.x, f0.y), pk2(f0.z, f0.w), pk2(f1.x, f1.y), pk2(f1.z, f1.w) };
    bf16x8 r; __builtin_memcpy(&r, &v, 16); return r;
}
__device__ __forceinline__ float bf2f(short s) {
    return __uint_as_float(((unsigned)(unsigned short)s) << 16);
}

// ============ fused highwayNet forward: 512 WGs x 512 threads, 8 heroes/WG, 2 WGs/CU ============
__global__ __launch_bounds__(512, 4) void highway_fused(
    const float* __restrict__ hist,  const float* __restrict__ nbrs,
    const float* __restrict__ Wip,   const float* __restrict__ bip,
    const float* __restrict__ WihE,  const float* __restrict__ WhhE,
    const float* __restrict__ bihE,  const float* __restrict__ bhhE,
    const float* __restrict__ Wdyn,  const float* __restrict__ bdyn,
    const float* __restrict__ Wnbr,  const float* __restrict__ bnbr,
    const float* __restrict__ WihD,  const float* __restrict__ WhhD,
    const float* __restrict__ bihD,  const float* __restrict__ bhhD,
    const float* __restrict__ Wop,   const float* __restrict__ bop,
    const int*   __restrict__ seg,
    float* __restrict__ fut)                        // [T_OUT][BHERO][2]
{
    __shared__ __align__(16) char lds_raw[LDS_TOTAL];
    auto slab   = (short (*)[HEROES][EROW])  lds_raw;               // [17][8][EROW]
    auto rela   = (short (*)[RROW])         (lds_raw + OFF_RELA);   // [256][RROW]
    auto pmax   = (float (*)[ENC])          (lds_raw + OFF_PMAX);   // [16][64]
    auto hist_s = (short (*)[HEROES][DROW])  lds_raw;               // [26][8][DROW]
    auto enc_s  = (float (*)[68])           (lds_raw + OFF_ENC);    // [8][68]
    auto wop_s  = (float (*)[DEC])          (lds_raw + OFF_WOP);    // [2][128]
    auto wip_s  = (float (*)[2])            (lds_raw + OFF_WIP);    // [32][2]
    auto bip_s  = (float*)                  (lds_raw + OFF_BIP);    // [32]
    auto bop_s  = (float*)                  (lds_raw + OFF_BOP);    // [2]

    const int b0  = blockIdx.x * HEROES;
    const int n0  = blockIdx.x * (HEROES * K_NBR);  // 256 neighbor rows per WG
    const int tid = threadIdx.x;
    const int w = tid >> 6, l = tid & 63, r = l & 15, lg = l >> 4;
    const int u0 = w * 16;
    const int r8 = r & 7;                           // A-row (heroes 0..7; lanes 8-15 duplicate)
    const bool lowhalf = (l < 32);
    const int row0 = lowhalf ? (4 * lg) : (4 * (lg - 2) + 2);   // this thread's 2 cell-rows

    // ---------------- P0: consts + zero slab0 h ----------------
    if (tid < EMB) {
        wip_s[tid][0] = Wip[2 * tid];
        wip_s[tid][1] = Wip[2 * tid + 1];
        bip_s[tid]    = bip[tid];
    }
    if (tid < 2 * DEC) wop_s[tid >> 7][tid & 127] = Wop[tid];
    if (tid < 2)       bop_s[tid] = bop[tid];
    slab[0][tid >> 6][32 + (tid & 63)] = 0;         // 512 = 8*64 exactly

    // encoder B-frags (waves 0-3) / nbr B-frag (waves 4-7: wave i owns col-tile i)
    bf16x8 BfE[4][3];
    float  biasjE[4];
    bf16x8 BfN;
    float  biasn = 0.f;
    if (tid < 256) {
        #pragma unroll
        for (int j = 0; j < 4; ++j) {
            const int col = j * ENC + u0 + r;
            biasjE[j] = bihE[col] + bhhE[col];
            #pragma unroll
            for (int c = 0; c < 3; ++c) {
                const float* src = (c == 0) ? (WihE + (size_t)col * EMB + 8 * lg)
                                            : (WhhE + (size_t)col * ENC + (c - 1) * 32 + 8 * lg);
                BfE[j][c] = mk_frag(*(const float4*)src, *(const float4*)(src + 4));
            }
        }
    } else {
        const int ct  = w - 4;
        const int col = ct * 16 + r;
        biasn = bnbr[col];
        const float* src = Wnbr + (size_t)col * (2 * T_IN) + 8 * lg;
        BfN = mk_frag(*(const float4*)src, *(const float4*)(src + 4));
    }
    __syncthreads();

    // ---------------- P1: emb prefill (waves 0-3) | rela tile 0 (waves 4-7) ----------------
    if (tid < 256) {
        const int task = tid >> 1;                  // 128 tasks: (t, m)
        const int t = task >> 3, m = task & 7;
        const int c0 = (tid & 1) * 16;
        float2 hv = *(const float2*)&hist[((size_t)t * BHERO + b0 + m) * 2];
        #pragma unroll
        for (int jb = 0; jb < 2; ++jb) {
            float e[8];
            #pragma unroll
            for (int q = 0; q < 8; ++q) {
                int j = c0 + jb * 8 + q;
                e[q] = lrelu(hv.x * wip_s[j][0] + hv.y * wip_s[j][1] + bip_s[j]);
            }
            uint4 v = { pk2(e[0],e[1]), pk2(e[2],e[3]), pk2(e[4],e[5]), pk2(e[6],e[7]) };
            __builtin_memcpy(&slab[t][m][c0 + jb * 8], &v, 16);
        }
    } else {
        const int x  = tid - 256;                   // 256 tasks: 16 rows x 16 timesteps
        const int n  = x & 15;
        const int ts = x >> 4;
        const int hb = seg[n0 + n];
        float2 hv = *(const float2*)&hist[((size_t)ts * BHERO + hb) * 2];
        float2 nv = *(const float2*)&nbrs[((size_t)ts * N_NBR + n0 + n) * 2];
        ((unsigned*)&rela[n][0])[ts] = pk2(hv.x - nv.x, hv.y - nv.y);
    }
    float cE0 = 0.f, cE1 = 0.f;                     // encoder cell states (2 cells/thread)
    __syncthreads();

    // ---------------- P2: encoder LSTM (waves 0-3) || nbr stage+GEMM (waves 4-7) ----------------
    {
        const short* rp = (const short*)lds_raw + r8 * EROW;
        short*       wp = (short*)lds_raw + SLABE + row0 * EROW + (32 + u0 + r);
        const int    x  = tid - 256;
        #pragma unroll 1
        for (int t = 0; t < T_IN; ++t) {
            if (tid < 256) {
                bf16x8 a0 = *(const bf16x8*)(rp + (0 + lg) * 8);
                bf16x8 a1 = *(const bf16x8*)(rp + (4 + lg) * 8);
                bf16x8 a2 = *(const bf16x8*)(rp + (8 + lg) * 8);
                f32x4 acc[4];
                #pragma unroll
                for (int j = 0; j < 4; ++j) {
                    acc[j] = (f32x4){biasjE[j], biasjE[j], biasjE[j], biasjE[j]};
                    acc[j] = __builtin_amdgcn_mfma_f32_16x16x32_bf16(a0, BfE[j][0], acc[j], 0, 0, 0);
                    acc[j] = __builtin_amdgcn_mfma_f32_16x16x32_bf16(a1, BfE[j][1], acc[j], 0, 0, 0);
                    acc[j] = __builtin_amdgcn_mfma_f32_16x16x32_bf16(a2, BfE[j][2], acc[j], 0, 0, 0);
                }
                // redistribute: lanes>=32 take q=2,3 cells of lanes<32 (rows row0,row0+1)
                float g0[4], g1[4];
                #pragma unroll
                for (int j = 0; j < 4; ++j) {
                    float t2 = __shfl(acc[j][2], l & 31);
                    float t3 = __shfl(acc[j][3], l & 31);
                    g0[j] = lowhalf ? acc[j][0] : t2;
                    g1[j] = lowhalf ? acc[j][1] : t3;
                }
                float i0 = sigm(g0[0]), f0 = sigm(g0[1]), G0 = tanhv(g0[2]), o0 = sigm(g0[3]);
                float i1 = sigm(g1[0]), f1 = sigm(g1[1]), G1 = tanhv(g1[2]), o1 = sigm(g1[3]);
                cE0 = fmaf(f0, cE0, i0 * G0);
                cE1 = fmaf(f1, cE1, i1 * G1);
                unsigned u = pk2(o0 * tanhv(cE0), o1 * tanhv(cE1));
                wp[0]    = (short)u;
                wp[EROW] = (short)(u >> 16);
            } else {
                if (t < T_IN - 1) {                 // stage tile t+1
                    const int n  = 16 * (t + 1) + (x & 15);
                    const int ts = x >> 4;
                    const int hb = seg[n0 + n];
                    float2 hv = *(const float2*)&hist[((size_t)ts * BHERO + hb) * 2];
                    float2 nv = *(const float2*)&nbrs[((size_t)ts * N_NBR + n0 + n) * 2];
                    ((unsigned*)&rela[n][0])[ts] = pk2(hv.x - nv.x, hv.y - nv.y);
                }
                // GEMM tile t (staged last iter): wave ct covers cols ct*16..+15
                bf16x8 a = *(const bf16x8*)&rela[t * 16 + r][8 * lg];
                f32x4 acc = {biasn, biasn, biasn, biasn};
                acc = __builtin_amdgcn_mfma_f32_16x16x32_bf16(a, BfN, acc, 0, 0, 0);
                float m4 = fmaxf(fmaxf(acc[0], acc[1]), fmaxf(acc[2], acc[3]));
                m4 = fmaxf(m4, __shfl_xor(m4, 16));
                m4 = fmaxf(m4, __shfl_xor(m4, 32));
                if (l < 16) pmax[t][(w - 4) * 16 + r] = m4;
            }
            __syncthreads();
            rp += SLABE; wp += SLABE;
        }
    }

    // ---------------- P3: enc_s = [hist_e | scene_d] + zero decoder slab 0 ----------------
    {
        const int m = tid >> 6, col = tid & 63;     // 512 tasks exactly
        const float* wd = Wdyn + (size_t)(col & 31) * ENC;
        float a = bdyn[col & 31];
        if (col < 32) {
            const short* hp = &slab[T_IN][m][32];
            #pragma unroll 8
            for (int k = 0; k < ENC; ++k) a = fmaf(bf2f(hp[k]), wd[k], a);
        } else {
            #pragma unroll 8
            for (int k = 0; k < ENC; ++k) {
                float sv = lrelu(fmaxf(pmax[2 * m][k], pmax[2 * m + 1][k]));
                a = fmaf(sv, wd[k], a);
            }
        }
        // write AFTER reads? enc_s is disjoint from slab[16]/pmax, safe within phase
        enc_s[m][col] = lrelu(a);
        // zero decoder slab 0 (bytes 0..2175; disjoint from slab[16]@26624+ and pmax@48768+)
        for (int i = tid; i < SLABD; i += 512) ((short*)hist_s)[i] = 0;
    }
    __syncthreads();

    // ---------------- P4: decoder frags + xw prologue + 25-step LSTM ----------------
    bf16x8 BfD[4][4];
    float  biasjD[4];
    #pragma unroll
    for (int j = 0; j < 4; ++j) {
        const int col = j * DEC + u0 + r;
        biasjD[j] = bihD[col] + bhhD[col];
        #pragma unroll
        for (int c = 0; c < 4; ++c) {
            const float* src = WhhD + (size_t)col * DEC + c * 32 + 8 * lg;
            BfD[j][c] = mk_frag(*(const float4*)src, *(const float4*)(src + 4));
        }
    }
    f32x4 xwf[4];
    {
        bf16x8 aE[2];
        #pragma unroll
        for (int c = 0; c < 2; ++c) {
            float4 f0 = *(const float4*)&enc_s[r8][c * 32 + 8 * lg];
            float4 f1 = *(const float4*)&enc_s[r8][c * 32 + 8 * lg + 4];
            aE[c] = mk_frag(f0, f1);
        }
        #pragma unroll
        for (int j = 0; j < 4; ++j) {
            const int col = j * DEC + u0 + r;
            f32x4 a = {biasjD[j], biasjD[j], biasjD[j], biasjD[j]};
            #pragma unroll
            for (int c = 0; c < 2; ++c) {
                const float* src = WihD + (size_t)col * (2 * DYN) + c * 32 + 8 * lg;
                a = __builtin_amdgcn_mfma_f32_16x16x32_bf16(
                        aE[c], mk_frag(*(const float4*)src, *(const float4*)(src + 4)), a, 0, 0, 0);
            }
            xwf[j] = a;
        }
    }

    float c0 = 0.f, c1 = 0.f;                       // decoder cell states (2 cells/thread)
    {
        const short* rp = (const short*)lds_raw + r8 * DROW;
        short*       wp = (short*)lds_raw + SLABD + row0 * DROW + (u0 + r);
        #pragma unroll 1
        for (int t = 0; t < T_OUT; ++t) {
            bf16x8 a_[4];
            #pragma unroll
            for (int c = 0; c < 4; ++c)
                a_[c] = *(const bf16x8*)(rp + (4 * c + lg) * 8);
            f32x4 acc[4];
            #pragma unroll
            for (int j = 0; j < 4; ++j) {
                acc[j] = xwf[j];
                #pragma unroll
                for (int c = 0; c < 4; ++c)
                    acc[j] = __builtin_amdgcn_mfma_f32_16x16x32_bf16(a_[c], BfD[j][c], acc[j], 0, 0, 0);
            }
            float g0[4], g1[4];
            #pragma unroll
            for (int j = 0; j < 4; ++j) {
                float t2 = __shfl(acc[j][2], l & 31);
                float t3 = __shfl(acc[j][3], l & 31);
                g0[j] = lowhalf ? acc[j][0] : t2;
                g1[j] = lowhalf ? acc[j][1] : t3;
            }
            float i0 = sigm(g0[0]), f0 = sigm(g0[1]), G0 = tanhv(g0[2]), o0 = sigm(g0[3]);
            float i1 = sigm(g1[0]), f1 = sigm(g1[1]), G1 = tanhv(g1[2]), o1 = sigm(g1[3]);
            c0 = fmaf(f0, c0, i0 * G0);
            c1 = fmaf(f1, c1, i1 * G1);
            unsigned u = pk2(o0 * tanhv(c0), o1 * tanhv(c1));
            wp[0]    = (short)u;
            wp[DROW] = (short)(u >> 16);
            __syncthreads();                        // h(t) ready (slab t+1 was unread)
            rp += SLABD; wp += SLABD;
        }
    }

    // ---------------- P5: deferred output head (200 tasks) ----------------
    if (tid < T_OUT * HEROES) {
        const int t = tid >> 3, m = tid & 7;
        const short* hp = &hist_s[t + 1][m][0];
        float o0 = bop_s[0], o1 = bop_s[1];
        #pragma unroll
        for (int ub = 0; ub < DEC / 8; ++ub) {
            bf16x8 hv = *(const bf16x8*)(hp + ub * 8);
            #pragma unroll
            for (int e = 0; e < 8; ++e) {
                float h = bf2f(hv[e]);
                o0 = fmaf(h, wop_s[0][ub * 8 + e], o0);
                o1 = fmaf(h, wop_s[1][ub * 8 + e], o1);
            }
        }
        *(float2*)(fut + ((size_t)t * BHERO + b0 + m) * 2) = make_float2(o0, o1);
    }
}

extern "C" void kernel_launch(void* const* d_in, const int* in_sizes, int n_in,
                              void* d_out, int out_size, void* d_ws, size_t ws_size,
                              hipStream_t stream) {
    (void)d_ws; (void)ws_size; (void)in_sizes; (void)n_in; (void)out_size;
    const float* hist  = (const float*)d_in[0];
    const float* nbrs  = (const float*)d_in[1];
    const float* Wip   = (const float*)d_in[2];
    const float* bip   = (const float*)d_in[3];
    const float* Wih_e = (const float*)d_in[4];
    const float* Whh_e = (const float*)d_in[5];
    const float* bih_e = (const float*)d_in[6];
    const float* bhh_e = (const float*)d_in[7];
    const float* Wdyn  = (const float*)d_in[8];
    const float* bdyn  = (const float*)d_in[9];
    const float* Wnbr  = (const float*)d_in[10];
    const float* bnbr  = (const float*)d_in[11];
    const float* Wih_d = (const float*)d_in[12];
    const float* Whh_d = (const float*)d_in[13];
    const float* bih_d = (const float*)d_in[14];
    const float* bhh_d = (const float*)d_in[15];
    const float* Wop   = (const float*)d_in[16];
    const float* bop   = (const float*)d_in[17];
    const int*   seg   = (const int*)d_in[18];
    float* fut = (float*)d_out;

    hipLaunchKernelGGL(highway_fused, dim3(BHERO / HEROES), dim3(512), 0, stream,
                       hist, nbrs, Wip, bip, Wih_e, Whh_e, bih_e, bhh_e, Wdyn, bdyn,
                       Wnbr, bnbr, Wih_d, Whh_d, bih_d, bhh_d, Wop, bop, seg, fut);
}

// Round 8
// 67.560 us; speedup vs baseline: 1.0399x; 1.0399x over previous
//
#include <hip/hip_runtime.h>
#include <hip/hip_bf16.h>

#define T_IN   16
#define T_OUT  25
#define BHERO  4096
#define K_NBR  32
#define N_NBR  (BHERO * K_NBR)
#define ENC    64
#define DEC    128
#define DYN    32
#define EMB    32

#define EROW   104        // encoder slab row: [emb 32 | h 64] + pad (208 B)
#define DROW   136        // decoder slab row: 128 bf16 + pad (272 B)
#define RROW   40         // rela row: 32 feat + 8 pad (80 B)
#define SLABE_S (16 * EROW)   // shorts per encoder slab (3328 B)
#define SLABD_S (16 * DROW)   // shorts per decoder slab (4352 B)

// ---- LDS layout (byte offsets; phases overlay) ----
// Encoder phase: slab[17][16][EROW] @0 (56576) | rela[512][RROW] @56576 (40960) | pmax[32][64] @97536 (8192)
// Decoder phase: hist_s[26][16][DROW] @0 (113152)
// Exchange bufs: bufA[128][20] f32 @113152 (10240) | bufB[128][18] float2 @123392 (18432)
// Persistent:    enc_s[16][68] @141824 | wop @146176 | wip @147200 | bip @147456 | bop @147584
#define OFF_RELA   56576
#define OFF_PMAX   97536
#define OFF_BUFA   113152
#define OFF_BUFB   123392
#define OFF_ENC    141824
#define OFF_WOP    146176
#define OFF_WIP    147200
#define OFF_BIP    147456
#define OFF_BOP    147584
#define LDS_TOTAL  147592     // 144.1 KB < 160 KB

typedef __attribute__((ext_vector_type(8))) short bf16x8;   // 8 bf16 in 4 VGPRs
typedef __attribute__((ext_vector_type(4))) float f32x4;    // MFMA 16x16 C/D frag

__device__ __forceinline__ float lrelu(float x) { return x >= 0.f ? x : 0.1f * x; }
__device__ __forceinline__ float rcpf(float x)  { return __builtin_amdgcn_rcpf(x); }
__device__ __forceinline__ float sigm(float x)  { return rcpf(1.f + __expf(-x)); }
__device__ __forceinline__ float tanhv(float x) {
    return fmaf(2.f, rcpf(1.f + __expf(-2.f * x)), -1.f);
}
__device__ __forceinline__ short f2bf(float x) {
    __hip_bfloat16 b = __float2bfloat16(x);
    short s; __builtin_memcpy(&s, &b, 2); return s;
}
__device__ __forceinline__ unsigned pk2(float lo, float hi) {
    __hip_bfloat162 p = __float22bfloat162_rn(make_float2(lo, hi));
    unsigned u; __builtin_memcpy(&u, &p, 4); return u;
}
__device__ __forceinline__ bf16x8 mk_frag(float4 f0, float4 f1) {
    uint4 v = { pk2(f0.x, f0.y), pk2(f0.z, f0.w), pk2(f1.x, f1.y), pk2(f1.z, f1.w) };
    bf16x8 r; __builtin_memcpy(&r, &v, 16); return r;
}
__device__ __forceinline__ float bf2f(short s) {
    return __uint_as_float(((unsigned)(unsigned short)s) << 16);
}

// ====== fused highwayNet fwd: 256 WGs x 1024 threads (16 waves = 4/SIMD), 16 heroes/WG ======
__global__ __launch_bounds__(1024, 4) void highway_fused(
    const float* __restrict__ hist,  const float* __restrict__ nbrs,
    const float* __restrict__ Wip,   const float* __restrict__ bip,
    const float* __restrict__ WihE,  const float* __restrict__ WhhE,
    const float* __restrict__ bihE,  const float* __restrict__ bhhE,
    const float* __restrict__ Wdyn,  const float* __restrict__ bdyn,
    const float* __restrict__ Wnbr,  const float* __restrict__ bnbr,
    const float* __restrict__ WihD,  const float* __restrict__ WhhD,
    const float* __restrict__ bihD,  const float* __restrict__ bhhD,
    const float* __restrict__ Wop,   const float* __restrict__ bop,
    const int*   __restrict__ seg,
    float* __restrict__ fut)                        // [T_OUT][BHERO][2]
{
    __shared__ __align__(16) char lds_raw[LDS_TOTAL];
    auto slab   = (short (*)[16][EROW])  lds_raw;                   // [17][16][EROW]
    auto rela   = (short (*)[RROW])     (lds_raw + OFF_RELA);       // [512][RROW]
    auto pmax   = (float (*)[ENC])      (lds_raw + OFF_PMAX);       // [32][64]
    auto hist_s = (short (*)[16][DROW])  lds_raw;                   // [26][16][DROW]
    auto bufA   = (float (*)[20])       (lds_raw + OFF_BUFA);       // [128][20]  (i*g)
    auto bufB   = (float2 (*)[18])      (lds_raw + OFF_BUFB);       // [128][18]  (sf,so)
    auto enc_s  = (float (*)[68])       (lds_raw + OFF_ENC);        // [16][68]
    auto wop_s  = (float (*)[DEC])      (lds_raw + OFF_WOP);        // [2][128]
    auto wip_s  = (float (*)[2])        (lds_raw + OFF_WIP);        // [32][2]
    auto bip_s  = (float*)              (lds_raw + OFF_BIP);        // [32]
    auto bop_s  = (float*)              (lds_raw + OFF_BOP);        // [2]

    const int b0  = blockIdx.x * 16;
    const int n0  = blockIdx.x * 512;               // first neighbor row of this WG
    const int tid = threadIdx.x;
    const int w = tid >> 6, l = tid & 63, r = l & 15, lg = l >> 4;

    // ---------------- P0: consts + zero slab0 h + B-frag prologues ----------------
    if (tid < EMB) {
        wip_s[tid][0] = Wip[2 * tid];
        wip_s[tid][1] = Wip[2 * tid + 1];
        bip_s[tid]    = bip[tid];
    }
    if (tid < 2 * DEC) wop_s[tid >> 7][tid & 127] = Wop[tid];
    if (tid < 2)       bop_s[tid] = bop[tid];
    slab[0][tid >> 6][32 + (tid & 63)] = 0;         // 1024 = 16*64 exactly

    // encoder B-frags (waves 0-3) / nbr B-frags (waves 4-7); waves 8-15: none
    bf16x8 BfE[4][3];
    float  biasE[4];
    bf16x8 BfN[2];
    float  biasn[2] = {0.f, 0.f};
    if (tid < 256) {
        const int u0e = w * 16;
        #pragma unroll
        for (int j = 0; j < 4; ++j) {
            const int col = j * ENC + u0e + r;
            biasE[j] = bihE[col] + bhhE[col];
            #pragma unroll
            for (int c = 0; c < 3; ++c) {
                const float* src = (c == 0) ? (WihE + (size_t)col * EMB + 8 * lg)
                                            : (WhhE + (size_t)col * ENC + (c - 1) * 32 + 8 * lg);
                BfE[j][c] = mk_frag(*(const float4*)src, *(const float4*)(src + 4));
            }
        }
    } else if (tid < 512) {
        const int i = w - 4;
        const int ct0 = (i & 1) * 2;
        #pragma unroll
        for (int cc2 = 0; cc2 < 2; ++cc2) {
            const int col = (ct0 + cc2) * 16 + r;
            biasn[cc2] = bnbr[col];
            const float* src = Wnbr + (size_t)col * (2 * T_IN) + 8 * lg;
            BfN[cc2] = mk_frag(*(const float4*)src, *(const float4*)(src + 4));
        }
    }
    __syncthreads();

    // ---------------- P1: emb prefill (waves 0-3) | rela pair 0 (waves 4-7) ----------------
    if (tid < 256) {
        const int t = tid >> 4, m = tid & 15;
        float2 hv = *(const float2*)&hist[((size_t)t * BHERO + b0 + m) * 2];
        #pragma unroll
        for (int jb = 0; jb < 4; ++jb) {
            float e[8];
            #pragma unroll
            for (int q = 0; q < 8; ++q) {
                int j = jb * 8 + q;
                e[q] = lrelu(hv.x * wip_s[j][0] + hv.y * wip_s[j][1] + bip_s[j]);
            }
            uint4 v = { pk2(e[0],e[1]), pk2(e[2],e[3]), pk2(e[4],e[5]), pk2(e[6],e[7]) };
            __builtin_memcpy(&slab[t][m][jb * 8], &v, 16);
        }
    } else if (tid < 512) {
        const int x  = tid - 256;
        const int n  = x & 31;                      // rows 0..31 (pair 0)
        const int ts = x >> 5;                      // 0..7 (also ts+8)
        const int hb = seg[n0 + n];
        float2 h0 = *(const float2*)&hist[((size_t)ts * BHERO + hb) * 2];
        float2 v0 = *(const float2*)&nbrs[((size_t)ts * N_NBR + n0 + n) * 2];
        float2 h1 = *(const float2*)&hist[((size_t)(ts + 8) * BHERO + hb) * 2];
        float2 v1 = *(const float2*)&nbrs[((size_t)(ts + 8) * N_NBR + n0 + n) * 2];
        unsigned* dst = (unsigned*)&rela[n][0];
        dst[ts]     = pk2(h0.x - v0.x, h0.y - v0.y);
        dst[ts + 8] = pk2(h1.x - v1.x, h1.y - v1.y);
    }
    f32x4 cstE = {0.f, 0.f, 0.f, 0.f};
    __syncthreads();

    // ---------------- P2: encoder LSTM (waves 0-3) || nbr pipeline (waves 4-7) ----------------
    {
        const short* rp  = (const short*)lds_raw + r * EROW;
        short*       wpE = (short*)lds_raw + SLABE_S + (4 * lg) * EROW + (32 + w * 16 + r);
        const int    x   = tid - 256;
        #pragma unroll 1
        for (int t = 0; t < T_IN; ++t) {
            if (tid < 256) {
                bf16x8 a0 = *(const bf16x8*)(rp + (0 + lg) * 8);
                bf16x8 a1 = *(const bf16x8*)(rp + (4 + lg) * 8);
                bf16x8 a2 = *(const bf16x8*)(rp + (8 + lg) * 8);
                f32x4 acc[4];
                #pragma unroll
                for (int j = 0; j < 4; ++j) {
                    acc[j] = (f32x4){biasE[j], biasE[j], biasE[j], biasE[j]};
                    acc[j] = __builtin_amdgcn_mfma_f32_16x16x32_bf16(a0, BfE[j][0], acc[j], 0, 0, 0);
                    acc[j] = __builtin_amdgcn_mfma_f32_16x16x32_bf16(a1, BfE[j][1], acc[j], 0, 0, 0);
                    acc[j] = __builtin_amdgcn_mfma_f32_16x16x32_bf16(a2, BfE[j][2], acc[j], 0, 0, 0);
                }
                float hq[4];
                #pragma unroll
                for (int q = 0; q < 4; ++q) {
                    float ii = sigm(acc[0][q]);
                    float ff = sigm(acc[1][q]);
                    float gg = tanhv(acc[2][q]);
                    float oo = sigm(acc[3][q]);
                    float cc = fmaf(ff, cstE[q], ii * gg);
                    cstE[q] = cc;
                    hq[q] = oo * tanhv(cc);
                }
                unsigned u01 = pk2(hq[0], hq[1]), u23 = pk2(hq[2], hq[3]);
                wpE[0 * EROW] = (short)u01; wpE[1 * EROW] = (short)(u01 >> 16);
                wpE[2 * EROW] = (short)u23; wpE[3 * EROW] = (short)(u23 >> 16);
            } else if (tid < 512) {
                if (t < T_IN - 1) {                 // stage pair t+1
                    const int n  = 32 * (t + 1) + (x & 31);
                    const int ts = x >> 5;
                    const int hb = seg[n0 + n];
                    float2 h0 = *(const float2*)&hist[((size_t)ts * BHERO + hb) * 2];
                    float2 v0 = *(const float2*)&nbrs[((size_t)ts * N_NBR + n0 + n) * 2];
                    float2 h1 = *(const float2*)&hist[((size_t)(ts + 8) * BHERO + hb) * 2];
                    float2 v1 = *(const float2*)&nbrs[((size_t)(ts + 8) * N_NBR + n0 + n) * 2];
                    unsigned* dst = (unsigned*)&rela[n][0];
                    dst[ts]     = pk2(h0.x - v0.x, h0.y - v0.y);
                    dst[ts + 8] = pk2(h1.x - v1.x, h1.y - v1.y);
                }
                // GEMM pair t: wave i covers rt = 2t + (i>>1), 2 col-tiles
                const int i  = w - 4;
                const int rt = 2 * t + (i >> 1);
                const int ct0 = (i & 1) * 2;
                bf16x8 a = *(const bf16x8*)&rela[rt * 16 + r][8 * lg];
                #pragma unroll
                for (int cc2 = 0; cc2 < 2; ++cc2) {
                    f32x4 acc = {biasn[cc2], biasn[cc2], biasn[cc2], biasn[cc2]};
                    acc = __builtin_amdgcn_mfma_f32_16x16x32_bf16(a, BfN[cc2], acc, 0, 0, 0);
                    float m4 = fmaxf(fmaxf(acc[0], acc[1]), fmaxf(acc[2], acc[3]));
                    m4 = fmaxf(m4, __shfl_xor(m4, 16));
                    m4 = fmaxf(m4, __shfl_xor(m4, 32));
                    if (l < 16) pmax[rt][(ct0 + cc2) * 16 + r] = m4;
                }
            }
            __syncthreads();
            rp += SLABE_S; wpE += SLABE_S;
        }
    }

    // ---------------- P3: enc_s = [hist_e | scene_d] + zero decoder slab 0 ----------------
    {
        const int m = tid >> 6, col = tid & 63;     // 1024 tasks exactly
        const float* wd = Wdyn + (size_t)(col & 31) * ENC;
        float a = bdyn[col & 31];
        if (col < 32) {
            const short* hp = &slab[T_IN][m][32];
            #pragma unroll 8
            for (int k = 0; k < ENC; ++k) a = fmaf(bf2f(hp[k]), wd[k], a);
        } else {
            #pragma unroll 8
            for (int k = 0; k < ENC; ++k) {
                float sv = lrelu(fmaxf(pmax[2 * m][k], pmax[2 * m + 1][k]));
                a = fmaf(sv, wd[k], a);
            }
        }
        enc_s[m][col] = lrelu(a);
        for (int i = tid; i < SLABD_S; i += 1024) ((short*)hist_s)[i] = 0;
    }
    __syncthreads();

    // ---------------- P4: decoder, gate-split across 16 waves ----------------
    // wave w<8: gates (i,g) of unit-block ub=w; wave w>=8: gates (f,o) of ub=w-8.
    // Exchange: i*tanh(g) via bufA; (sigm(f),sigm(o)) via bufB. Each wave finalizes
    // 2 cells: ig-waves q=0,1 ; fo-waves q=2,3 (c-state split accordingly).
    const bool ig  = (w < 8);
    const int  ub  = w & 7;
    const int  u0d = ub * 16;
    const int  qb  = ig ? 0 : 2;
    const int  j0  = ig ? 0 : 1;                    // i or f
    const int  j1  = ig ? 2 : 3;                    // g or o
    bf16x8 BfD[2][4];
    float  biasD[2];
    {
        const int colA = j0 * DEC + u0d + r;
        const int colB = j1 * DEC + u0d + r;
        biasD[0] = bihD[colA] + bhhD[colA];
        biasD[1] = bihD[colB] + bhhD[colB];
        #pragma unroll
        for (int c = 0; c < 4; ++c) {
            const float* sA = WhhD + (size_t)colA * DEC + c * 32 + 8 * lg;
            const float* sB = WhhD + (size_t)colB * DEC + c * 32 + 8 * lg;
            BfD[0][c] = mk_frag(*(const float4*)sA, *(const float4*)(sA + 4));
            BfD[1][c] = mk_frag(*(const float4*)sB, *(const float4*)(sB + 4));
        }
    }
    f32x4 xwf0, xwf1;
    {
        bf16x8 aE[2];
        #pragma unroll
        for (int c = 0; c < 2; ++c) {
            float4 f0 = *(const float4*)&enc_s[r][c * 32 + 8 * lg];
            float4 f1 = *(const float4*)&enc_s[r][c * 32 + 8 * lg + 4];
            aE[c] = mk_frag(f0, f1);
        }
        const int colA = j0 * DEC + u0d + r;
        const int colB = j1 * DEC + u0d + r;
        xwf0 = (f32x4){biasD[0], biasD[0], biasD[0], biasD[0]};
        xwf1 = (f32x4){biasD[1], biasD[1], biasD[1], biasD[1]};
        #pragma unroll
        for (int c = 0; c < 2; ++c) {
            const float* sA = WihD + (size_t)colA * (2 * DYN) + c * 32 + 8 * lg;
            const float* sB = WihD + (size_t)colB * (2 * DYN) + c * 32 + 8 * lg;
            xwf0 = __builtin_amdgcn_mfma_f32_16x16x32_bf16(
                       aE[c], mk_frag(*(const float4*)sA, *(const float4*)(sA + 4)), xwf0, 0, 0, 0);
            xwf1 = __builtin_amdgcn_mfma_f32_16x16x32_bf16(
                       aE[c], mk_frag(*(const float4*)sB, *(const float4*)(sB + 4)), xwf1, 0, 0, 0);
        }
    }

    float c0 = 0.f, c1 = 0.f;                       // this wave's 2 cells (q = qb, qb+1)
    {
        const short* rp = (const short*)lds_raw + r * DROW;
        short*       wp = (short*)lds_raw + SLABD_S + (4 * lg + qb) * DROW + (u0d + r);
        float*  bArow = &bufA[u0d + r][0];
        float2* bBrow = &bufB[u0d + r][0];
        #pragma unroll 1
        for (int t = 0; t < T_OUT; ++t) {
            bf16x8 a_[4];
            #pragma unroll
            for (int c = 0; c < 4; ++c)
                a_[c] = *(const bf16x8*)(rp + (4 * c + lg) * 8);
            f32x4 acc0 = xwf0, acc1 = xwf1;
            #pragma unroll
            for (int c = 0; c < 4; ++c) {
                acc0 = __builtin_amdgcn_mfma_f32_16x16x32_bf16(a_[c], BfD[0][c], acc0, 0, 0, 0);
                acc1 = __builtin_amdgcn_mfma_f32_16x16x32_bf16(a_[c], BfD[1][c], acc1, 0, 0, 0);
            }
            float sA0, sA1, sf0, so0, sf1, so1;     // this wave's finalization inputs
            if (ig) {
                float s0 = sigm(acc0[0]) * tanhv(acc1[0]);
                float s1 = sigm(acc0[1]) * tanhv(acc1[1]);
                float s2 = sigm(acc0[2]) * tanhv(acc1[2]);
                float s3 = sigm(acc0[3]) * tanhv(acc1[3]);
                *(float4*)&bArow[4 * lg] = make_float4(s0, s1, s2, s3);
                sA0 = s0; sA1 = s1;
            } else {
                float f0v = sigm(acc0[0]), o0v = sigm(acc1[0]);
                float f1v = sigm(acc0[1]), o1v = sigm(acc1[1]);
                float f2v = sigm(acc0[2]), o2v = sigm(acc1[2]);
                float f3v = sigm(acc0[3]), o3v = sigm(acc1[3]);
                *(float4*)&bBrow[4 * lg]     = make_float4(f0v, o0v, f1v, o1v);
                *(float4*)&bBrow[4 * lg + 2] = make_float4(f2v, o2v, f3v, o3v);
                sf0 = f2v; so0 = o2v; sf1 = f3v; so1 = o3v;
            }
            __syncthreads();                        // exchange ready
            if (ig) {
                float4 v = *(const float4*)&bBrow[4 * lg];
                sf0 = v.x; so0 = v.y; sf1 = v.z; so1 = v.w;
            } else {
                float2 sg = *(const float2*)&bArow[4 * lg + 2];
                sA0 = sg.x; sA1 = sg.y;
            }
            c0 = fmaf(sf0, c0, sA0);
            c1 = fmaf(sf1, c1, sA1);
            unsigned u = pk2(so0 * tanhv(c0), so1 * tanhv(c1));
            wp[0]    = (short)u;
            wp[DROW] = (short)(u >> 16);
            __syncthreads();                        // h(t) ready (slab t+1 was unread)
            rp += SLABD_S; wp += SLABD_S;
        }
    }

    // ---------------- P5: deferred output head (400 tasks) ----------------
    if (tid < T_OUT * 16) {
        const int t = tid >> 4, m = tid & 15;
        const short* hp = &hist_s[t + 1][m][0];
        float o0 = bop_s[0], o1 = bop_s[1];
        #pragma unroll
        for (int ubk = 0; ubk < DEC / 8; ++ubk) {
            bf16x8 hv = *(const bf16x8*)(hp + ubk * 8);
            #pragma unroll
            for (int e = 0; e < 8; ++e) {
                float h = bf2f(hv[e]);
                o0 = fmaf(h, wop_s[0][ubk * 8 + e], o0);
                o1 = fmaf(h, wop_s[1][ubk * 8 + e], o1);
            }
        }
        *(float2*)(fut + ((size_t)t * BHERO + b0 + m) * 2) = make_float2(o0, o1);
    }
}

extern "C" void kernel_launch(void* const* d_in, const int* in_sizes, int n_in,
                              void* d_out, int out_size, void* d_ws, size_t ws_size,
                              hipStream_t stream) {
    (void)d_ws; (void)ws_size; (void)in_sizes; (void)n_in; (void)out_size;
    const float* hist  = (const float*)d_in[0];
    const float* nbrs  = (const float*)d_in[1];
    const float* Wip   = (const float*)d_in[2];
    const float* bip   = (const float*)d_in[3];
    const float* Wih_e = (const float*)d_in[4];
    const float* Whh_e = (const float*)d_in[5];
    const float* bih_e = (const float*)d_in[6];
    const float* bhh_e = (const float*)d_in[7];
    const float* Wdyn  = (const float*)d_in[8];
    const float* bdyn  = (const float*)d_in[9];
    const float* Wnbr  = (const float*)d_in[10];
    const float* bnbr  = (const float*)d_in[11];
    const float* Wih_d = (const float*)d_in[12];
    const float* Whh_d = (const float*)d_in[13];
    const float* bih_d = (const float*)d_in[14];
    const float* bhh_d = (const float*)d_in[15];
    const float* Wop   = (const float*)d_in[16];
    const float* bop   = (const float*)d_in[17];
    const int*   seg   = (const int*)d_in[18];
    float* fut = (float*)d_out;

    hipLaunchKernelGGL(highway_fused, dim3(BHERO / 16), dim3(1024), 0, stream,
                       hist, nbrs, Wip, bip, Wih_e, Whh_e, bih_e, bhh_e, Wdyn, bdyn,
                       Wnbr, bnbr, Wih_d, Whh_d, bih_d, bhh_d, Wop, bop, seg, fut);
}

// Round 9
// 63.584 us; speedup vs baseline: 1.1050x; 1.0625x over previous
//
#include <hip/hip_runtime.h>
#include <hip/hip_bf16.h>

#define T_IN   16
#define T_OUT  25
#define BHERO  4096
#define K_NBR  32
#define N_NBR  (BHERO * K_NBR)
#define ENC    64
#define DEC    128
#define DYN    32
#define EMB    32

#define EROW   104        // encoder slab row: [emb 32 | h 64] + pad (208 B)
#define DROW   136        // decoder slab row: 128 bf16 + pad (272 B)
#define RROW   40         // rela row: 32 feat + 8 pad (80 B)
#define SLABE  (16 * EROW * 2)   // 3328 B per encoder slab
#define SLABD  (16 * DROW * 2)   // 4352 B per decoder slab

// ---- LDS layout (byte offsets into one raw pool; phases overlay) ----
#define OFF_RELA   56576
#define OFF_PMAX   97536
#define OFF_ENC    113152
#define OFF_WOP    117504
#define OFF_WIP    118528
#define OFF_BIP    118784
#define OFF_BOP    118912
#define LDS_TOTAL  118928

#define L2E 1.44269504f   // log2(e); gate pre-scales fold the exp-arg mul into W/b

typedef __attribute__((ext_vector_type(8))) short bf16x8;   // 8 bf16 in 4 VGPRs
typedef __attribute__((ext_vector_type(4))) float f32x4;    // MFMA 16x16 C/D frag

__device__ __forceinline__ float lrelu(float x) { return x >= 0.f ? x : 0.1f * x; }
__device__ __forceinline__ float rcpf(float x)  { return __builtin_amdgcn_rcpf(x); }
__device__ __forceinline__ float ex2(float x)   { return __builtin_amdgcn_exp2f(x); }
// Activations on PRESCALED arguments (weights/bias already x L2E, g-gate x 2*L2E):
__device__ __forceinline__ float sigm2(float x) { return rcpf(1.f + ex2(-x)); }           // sigma(x/L2E)
__device__ __forceinline__ float tanh2(float x) { return fmaf(2.f, rcpf(1.f + ex2(-x)), -1.f); } // tanh(x/(2 L2E))
__device__ __forceinline__ float tanhc(float c) {                                          // tanh(c), c unscaled
    return fmaf(2.f, rcpf(1.f + ex2(-2.f * L2E * c)), -1.f);
}
__device__ __forceinline__ short f2bf(float x) {
    __hip_bfloat16 b = __float2bfloat16(x);
    short s; __builtin_memcpy(&s, &b, 2); return s;
}
__device__ __forceinline__ unsigned pk2(float lo, float hi) {
    __hip_bfloat162 p = __float22bfloat162_rn(make_float2(lo, hi));
    unsigned u; __builtin_memcpy(&u, &p, 4); return u;
}
__device__ __forceinline__ bf16x8 mk_frag(float4 f0, float4 f1) {
    uint4 v = { pk2(f0.x, f0.y), pk2(f0.z, f0.w), pk2(f1.x, f1.y), pk2(f1.z, f1.w) };
    bf16x8 r; __builtin_memcpy(&r, &v, 16); return r;
}
__device__ __forceinline__ bf16x8 mk_frag_s(float4 f0, float4 f1, float s) {
    uint4 v = { pk2(f0.x*s, f0.y*s), pk2(f0.z*s, f0.w*s), pk2(f1.x*s, f1.y*s), pk2(f1.z*s, f1.w*s) };
    bf16x8 r; __builtin_memcpy(&r, &v, 16); return r;
}
__device__ __forceinline__ float bf2f(short s) {
    return __uint_as_float(((unsigned)(unsigned short)s) << 16);
}

// ================= fused highwayNet forward: 256 WGs x 512 threads, 16 heroes/WG =================
__global__ __launch_bounds__(512, 2) void highway_fused(
    const float* __restrict__ hist,  const float* __restrict__ nbrs,
    const float* __restrict__ Wip,   const float* __restrict__ bip,
    const float* __restrict__ WihE,  const float* __restrict__ WhhE,
    const float* __restrict__ bihE,  const float* __restrict__ bhhE,
    const float* __restrict__ Wdyn,  const float* __restrict__ bdyn,
    const float* __restrict__ Wnbr,  const float* __restrict__ bnbr,
    const float* __restrict__ WihD,  const float* __restrict__ WhhD,
    const float* __restrict__ bihD,  const float* __restrict__ bhhD,
    const float* __restrict__ Wop,   const float* __restrict__ bop,
    const int*   __restrict__ seg,
    float* __restrict__ fut)                        // [T_OUT][BHERO][2]
{
    __shared__ __align__(16) char lds_raw[LDS_TOTAL];
    auto slab   = (short (*)[16][EROW])  lds_raw;                   // [17][16][EROW]
    auto rela   = (short (*)[RROW])     (lds_raw + OFF_RELA);       // [512][RROW]
    auto pmax   = (float (*)[ENC])      (lds_raw + OFF_PMAX);       // [32][64]
    auto hist_s = (short (*)[16][DROW])  lds_raw;                   // [26][16][DROW]
    auto enc_s  = (float (*)[68])       (lds_raw + OFF_ENC);        // [16][68]
    auto wop_s  = (float (*)[DEC])      (lds_raw + OFF_WOP);        // [2][128]
    auto wip_s  = (float (*)[2])        (lds_raw + OFF_WIP);        // [32][2]
    auto bip_s  = (float*)              (lds_raw + OFF_BIP);        // [32]
    auto bop_s  = (float*)              (lds_raw + OFF_BOP);        // [2]

    const int b0  = blockIdx.x * 16;
    const int n0  = blockIdx.x * 512;               // first neighbor row of this WG
    const int tid = threadIdx.x;
    const int w = tid >> 6, l = tid & 63, r = l & 15, lg = l >> 4;

    // ---------------- P0: consts, zero slab0-h, frag prologues ----------------
    if (tid < EMB) {
        wip_s[tid][0] = Wip[2 * tid];
        wip_s[tid][1] = Wip[2 * tid + 1];
        bip_s[tid]    = bip[tid];
    }
    if (tid < 2 * DEC) wop_s[tid >> 7][tid & 127] = Wop[tid];
    if (tid < 2)       bop_s[tid] = bop[tid];
    for (int i = tid; i < 16 * ENC; i += 512) slab[0][i >> 6][32 + (i & 63)] = 0;

    // encoder B-frags (waves 0-3, prescaled) / nbr B-frags (waves 4-7, unscaled)
    bf16x8 BfE[4][3];
    float  biasE[4];
    bf16x8 BfN[2];
    float  biasn[2] = {0.f, 0.f};
    if (tid < 256) {
        #pragma unroll
        for (int j = 0; j < 4; ++j) {
            const float sj  = (j == 2) ? (2.f * L2E) : L2E;
            const int   col = j * ENC + w * 16 + r;
            biasE[j] = (bihE[col] + bhhE[col]) * sj;
            #pragma unroll
            for (int c = 0; c < 3; ++c) {
                const float* src = (c == 0) ? (WihE + (size_t)col * EMB + 8 * lg)
                                            : (WhhE + (size_t)col * ENC + (c - 1) * 32 + 8 * lg);
                BfE[j][c] = mk_frag_s(*(const float4*)src, *(const float4*)(src + 4), sj);
            }
        }
    } else {
        const int i = w - 4;
        const int ct0 = (i & 1) * 2;
        #pragma unroll
        for (int cc2 = 0; cc2 < 2; ++cc2) {
            const int col = (ct0 + cc2) * 16 + r;
            biasn[cc2] = bnbr[col];
            const float* src = Wnbr + (size_t)col * (2 * T_IN) + 8 * lg;
            BfN[cc2] = mk_frag(*(const float4*)src, *(const float4*)(src + 4));
        }
    }
    __syncthreads();                                // consts + slab0-h ready

    // ---------------- P1: emb prefill (waves 0-3) | rela pair 0 staging (waves 4-7) ----------------
    if (tid < 256) {
        const int t = tid >> 4, m = tid & 15;
        float2 hv = *(const float2*)&hist[((size_t)t * BHERO + b0 + m) * 2];
        #pragma unroll
        for (int jb = 0; jb < 4; ++jb) {
            float e[8];
            #pragma unroll
            for (int q = 0; q < 8; ++q) {
                int j = jb * 8 + q;
                e[q] = lrelu(hv.x * wip_s[j][0] + hv.y * wip_s[j][1] + bip_s[j]);
            }
            uint4 v = { pk2(e[0],e[1]), pk2(e[2],e[3]), pk2(e[4],e[5]), pk2(e[6],e[7]) };
            __builtin_memcpy(&slab[t][m][jb * 8], &v, 16);
        }
    } else {
        const int x = tid - 256;
        const int n  = x & 31;                      // rows 0..31 (pair 0)
        const int ts = x >> 5;                      // 0..7 (also ts+8)
        const int hb = seg[n0 + n];
        float2 h0 = *(const float2*)&hist[((size_t)ts * BHERO + hb) * 2];
        float2 v0 = *(const float2*)&nbrs[((size_t)ts * N_NBR + n0 + n) * 2];
        float2 h1 = *(const float2*)&hist[((size_t)(ts + 8) * BHERO + hb) * 2];
        float2 v1 = *(const float2*)&nbrs[((size_t)(ts + 8) * N_NBR + n0 + n) * 2];
        unsigned* dst = (unsigned*)&rela[n][0];
        dst[ts]     = pk2(h0.x - v0.x, h0.y - v0.y);
        dst[ts + 8] = pk2(h1.x - v1.x, h1.y - v1.y);
    }
    f32x4 cstE = {0.f, 0.f, 0.f, 0.f};              // cell state: hero 4*lg+q, unit w*16+r
    __syncthreads();                                // emb + rela pair 0 ready

    // ---------------- P2: encoder LSTM (waves 0-3) || nbr stage+GEMM pipeline (waves 4-7) ----------------
    {
        const char* rbase = lds_raw + (size_t)r * (EROW * 2);
        char*       wbase = lds_raw + SLABE + (size_t)(4 * lg) * (EROW * 2) + (size_t)(32 + w * 16 + r) * 2;
        const int   x = tid - 256;                  // valid for waves 4-7
        #pragma unroll 1
        for (int t = 0; t < T_IN; ++t) {
            if (tid < 256) {
                const short* rp = (const short*)rbase;
                bf16x8 a0 = *(const bf16x8*)(rp + (0 + lg) * 8);
                bf16x8 a1 = *(const bf16x8*)(rp + (4 + lg) * 8);
                bf16x8 a2 = *(const bf16x8*)(rp + (8 + lg) * 8);
                f32x4 acc[4];
                #pragma unroll
                for (int j = 0; j < 4; ++j) {
                    f32x4 aA = (f32x4){biasE[j], biasE[j], biasE[j], biasE[j]};
                    f32x4 aB = (f32x4){0.f, 0.f, 0.f, 0.f};
                    aA = __builtin_amdgcn_mfma_f32_16x16x32_bf16(a0, BfE[j][0], aA, 0, 0, 0);
                    aB = __builtin_amdgcn_mfma_f32_16x16x32_bf16(a1, BfE[j][1], aB, 0, 0, 0);
                    aA = __builtin_amdgcn_mfma_f32_16x16x32_bf16(a2, BfE[j][2], aA, 0, 0, 0);
                    acc[j] = aA + aB;
                }
                float hq[4];
                #pragma unroll
                for (int q = 0; q < 4; ++q) {
                    float ii = sigm2(acc[0][q]);
                    float ff = sigm2(acc[1][q]);
                    float gg = tanh2(acc[2][q]);
                    float oo = sigm2(acc[3][q]);
                    float cc = fmaf(ff, cstE[q], ii * gg);
                    cstE[q] = cc;
                    hq[q] = oo * tanhc(cc);
                }
                unsigned u01 = pk2(hq[0], hq[1]), u23 = pk2(hq[2], hq[3]);
                short* wp = (short*)wbase;
                wp[0 * EROW] = (short)u01; wp[1 * EROW] = (short)(u01 >> 16);
                wp[2 * EROW] = (short)u23; wp[3 * EROW] = (short)(u23 >> 16);
            } else {
                // stage pair t+1 (rows 32(t+1)..+31)
                if (t < T_IN - 1) {
                    const int n  = 32 * (t + 1) + (x & 31);
                    const int ts = x >> 5;
                    const int hb = seg[n0 + n];
                    float2 h0 = *(const float2*)&hist[((size_t)ts * BHERO + hb) * 2];
                    float2 v0 = *(const float2*)&nbrs[((size_t)ts * N_NBR + n0 + n) * 2];
                    float2 h1 = *(const float2*)&hist[((size_t)(ts + 8) * BHERO + hb) * 2];
                    float2 v1 = *(const float2*)&nbrs[((size_t)(ts + 8) * N_NBR + n0 + n) * 2];
                    unsigned* dst = (unsigned*)&rela[n][0];
                    dst[ts]     = pk2(h0.x - v0.x, h0.y - v0.y);
                    dst[ts + 8] = pk2(h1.x - v1.x, h1.y - v1.y);
                }
                // GEMM pair t (staged last iteration): wave i covers rt = 2t + (i>>1), 2 col-tiles
                const int i  = w - 4;
                const int rt = 2 * t + (i >> 1);
                const int ct0 = (i & 1) * 2;
                bf16x8 a = *(const bf16x8*)&rela[rt * 16 + r][8 * lg];
                #pragma unroll
                for (int cc2 = 0; cc2 < 2; ++cc2) {
                    f32x4 acc = {biasn[cc2], biasn[cc2], biasn[cc2], biasn[cc2]};
                    acc = __builtin_amdgcn_mfma_f32_16x16x32_bf16(a, BfN[cc2], acc, 0, 0, 0);
                    float m4 = fmaxf(fmaxf(acc[0], acc[1]), fmaxf(acc[2], acc[3]));
                    m4 = fmaxf(m4, __shfl_xor(m4, 16));
                    m4 = fmaxf(m4, __shfl_xor(m4, 32));
                    if (l < 16) pmax[rt][(ct0 + cc2) * 16 + r] = m4;
                }
            }
            __syncthreads();                        // h(t) + pair-(t+1) rela + pair-t pmax ready
            rbase += SLABE; wbase += SLABE;
        }
    }

    // ---------------- P3: enc_s = [hist_e | scene_d], zero decoder slab 0 ----------------
    #pragma unroll
    for (int it = 0; it < 2; ++it) {
        const int s = tid + 512 * it;               // 1024 tasks: (m, col)
        const int m = s >> 6, col = s & 63;
        const float* wd = Wdyn + (size_t)(col & 31) * ENC;
        float a = bdyn[col & 31];
        if (col < 32) {
            const short* hp = &slab[T_IN][m][32];
            #pragma unroll
            for (int kb = 0; kb < 8; ++kb) {
                bf16x8 hv = *(const bf16x8*)(hp + kb * 8);
                #pragma unroll
                for (int e = 0; e < 8; ++e)
                    a = fmaf(bf2f(hv[e]), wd[kb * 8 + e], a);
            }
        } else {
            #pragma unroll
            for (int kb = 0; kb < 16; ++kb) {
                float4 p0 = *(const float4*)&pmax[2 * m][kb * 4];
                float4 p1 = *(const float4*)&pmax[2 * m + 1][kb * 4];
                a = fmaf(lrelu(fmaxf(p0.x, p1.x)), wd[kb * 4 + 0], a);
                a = fmaf(lrelu(fmaxf(p0.y, p1.y)), wd[kb * 4 + 1], a);
                a = fmaf(lrelu(fmaxf(p0.z, p1.z)), wd[kb * 4 + 2], a);
                a = fmaf(lrelu(fmaxf(p0.w, p1.w)), wd[kb * 4 + 3], a);
            }
        }
        enc_s[m][col] = lrelu(a);
    }
    for (int i = tid; i < 16 * DROW; i += 512) ((short*)hist_s)[i] = 0;   // zero h(0)
    __syncthreads();                                // enc_s + decoder slab0 ready

    // ---------------- P4: decoder frags (prescaled) + xw prologue + 25-step LSTM ----------------
    const int u0 = w * 16;
    bf16x8 BfD[4][4];
    float  biasD[4];
    float  sjD[4];
    #pragma unroll
    for (int j = 0; j < 4; ++j) {
        const float sj  = (j == 2) ? (2.f * L2E) : L2E;
        const int   col = j * DEC + u0 + r;
        sjD[j]   = sj;
        biasD[j] = (bihD[col] + bhhD[col]) * sj;
        #pragma unroll
        for (int c = 0; c < 4; ++c) {
            const float* src = WhhD + (size_t)col * DEC + c * 32 + 8 * lg;
            BfD[j][c] = mk_frag_s(*(const float4*)src, *(const float4*)(src + 4), sj);
        }
    }
    f32x4 xwf[4];
    {
        bf16x8 aE[2];
        #pragma unroll
        for (int c = 0; c < 2; ++c) {
            float4 f0 = *(const float4*)&enc_s[r][c * 32 + 8 * lg];
            float4 f1 = *(const float4*)&enc_s[r][c * 32 + 8 * lg + 4];
            aE[c] = mk_frag(f0, f1);
        }
        #pragma unroll
        for (int j = 0; j < 4; ++j) {
            const int col = j * DEC + u0 + r;
            f32x4 a = {biasD[j], biasD[j], biasD[j], biasD[j]};
            #pragma unroll
            for (int c = 0; c < 2; ++c) {
                const float* src = WihD + (size_t)col * (2 * DYN) + c * 32 + 8 * lg;
                a = __builtin_amdgcn_mfma_f32_16x16x32_bf16(
                        aE[c], mk_frag_s(*(const float4*)src, *(const float4*)(src + 4), sjD[j]),
                        a, 0, 0, 0);
            }
            xwf[j] = a;
        }
    }

    f32x4 cst = {0.f, 0.f, 0.f, 0.f};
    {
        const char* rbase = lds_raw + (size_t)r * (DROW * 2);
        char*       wbase = lds_raw + SLABD + (size_t)(4 * lg) * (DROW * 2) + (size_t)(u0 + r) * 2;
        #pragma unroll 1
        for (int t = 0; t < T_OUT; ++t) {
            const short* rp = (const short*)rbase;
            bf16x8 a_[4];
            #pragma unroll
            for (int c = 0; c < 4; ++c)
                a_[c] = *(const bf16x8*)(rp + (4 * c + lg) * 8);
            f32x4 acc[4];
            #pragma unroll
            for (int j = 0; j < 4; ++j) {
                f32x4 aA = xwf[j];
                f32x4 aB = (f32x4){0.f, 0.f, 0.f, 0.f};
                aA = __builtin_amdgcn_mfma_f32_16x16x32_bf16(a_[0], BfD[j][0], aA, 0, 0, 0);
                aB = __builtin_amdgcn_mfma_f32_16x16x32_bf16(a_[1], BfD[j][1], aB, 0, 0, 0);
                aA = __builtin_amdgcn_mfma_f32_16x16x32_bf16(a_[2], BfD[j][2], aA, 0, 0, 0);
                aB = __builtin_amdgcn_mfma_f32_16x16x32_bf16(a_[3], BfD[j][3], aB, 0, 0, 0);
                acc[j] = aA + aB;
            }
            float hq[4];
            #pragma unroll
            for (int q = 0; q < 4; ++q) {
                float ii = sigm2(acc[0][q]);
                float ff = sigm2(acc[1][q]);
                float gg = tanh2(acc[2][q]);
                float oo = sigm2(acc[3][q]);
                float cc = fmaf(ff, cst[q], ii * gg);
                cst[q] = cc;
                hq[q] = oo * tanhc(cc);
            }
            unsigned u01 = pk2(hq[0], hq[1]), u23 = pk2(hq[2], hq[3]);
            short* wp = (short*)wbase;
            wp[0 * DROW] = (short)u01; wp[1 * DROW] = (short)(u01 >> 16);
            wp[2 * DROW] = (short)u23; wp[3 * DROW] = (short)(u23 >> 16);
            __syncthreads();                        // h(t) ready (slab t+1 was unread)
            rbase += SLABD; wbase += SLABD;
        }
    }

    // ---------------- P5: deferred output head ----------------
    if (tid < T_OUT * 16) {
        const int t = tid >> 4, m = tid & 15;
        const short* hp = &hist_s[t + 1][m][0];
        float o0 = bop_s[0], o1 = bop_s[1];
        #pragma unroll
        for (int ub = 0; ub < DEC / 8; ++ub) {
            bf16x8 hv = *(const bf16x8*)(hp + ub * 8);
            #pragma unroll
            for (int e = 0; e < 8; ++e) {
                float h = bf2f(hv[e]);
                o0 = fmaf(h, wop_s[0][ub * 8 + e], o0);
                o1 = fmaf(h, wop_s[1][ub * 8 + e], o1);
            }
        }
        *(float2*)(fut + ((size_t)t * BHERO + b0 + m) * 2) = make_float2(o0, o1);
    }
}

extern "C" void kernel_launch(void* const* d_in, const int* in_sizes, int n_in,
                              void* d_out, int out_size, void* d_ws, size_t ws_size,
                              hipStream_t stream) {
    (void)d_ws; (void)ws_size; (void)in_sizes; (void)n_in; (void)out_size;
    const float* hist  = (const float*)d_in[0];
    const float* nbrs  = (const float*)d_in[1];
    const float* Wip   = (const float*)d_in[2];
    const float* bip   = (const float*)d_in[3];
    const float* Wih_e = (const float*)d_in[4];
    const float* Whh_e = (const float*)d_in[5];
    const float* bih_e = (const float*)d_in[6];
    const float* bhh_e = (const float*)d_in[7];
    const float* Wdyn  = (const float*)d_in[8];
    const float* bdyn  = (const float*)d_in[9];
    const float* Wnbr  = (const float*)d_in[10];
    const float* bnbr  = (const float*)d_in[11];
    const float* Wih_d = (const float*)d_in[12];
    const float* Whh_d = (const float*)d_in[13];
    const float* bih_d = (const float*)d_in[14];
    const float* bhh_d = (const float*)d_in[15];
    const float* Wop   = (const float*)d_in[16];
    const float* bop   = (const float*)d_in[17];
    const int*   seg   = (const int*)d_in[18];
    float* fut = (float*)d_out;

    hipLaunchKernelGGL(highway_fused, dim3(BHERO / 16), dim3(512), 0, stream,
                       hist, nbrs, Wip, bip, Wih_e, Whh_e, bih_e, bhh_e, Wdyn, bdyn,
                       Wnbr, bnbr, Wih_d, Whh_d, bih_d, bhh_d, Wop, bop, seg, fut);
}